// Round 18
// baseline (220.733 us; speedup 1.0000x reference)
//
#include <hip/hip_runtime.h>
#include <hip/hip_bf16.h>

typedef __attribute__((ext_vector_type(8))) __bf16 bf16x8;
typedef __attribute__((ext_vector_type(8))) short short8;
typedef __attribute__((ext_vector_type(4))) short s16x4;
typedef __attribute__((ext_vector_type(4))) float f32x4;

#define LN 1024
#define NH 16
#define DKH 64

__device__ __forceinline__ short f2bf(float f) {
    unsigned u = __builtin_bit_cast(unsigned, f);
    u = u + 0x7fffu + ((u >> 16) & 1u);
    return (short)(u >> 16);
}
__device__ __forceinline__ float bf2f(short s) {
    return __builtin_bit_cast(float, ((unsigned)(unsigned short)s) << 16);
}

__device__ __forceinline__ void gl_lds16(const short* g, short* l) {
    __builtin_amdgcn_global_load_lds(
        (const __attribute__((address_space(1))) void*)g,
        (__attribute__((address_space(3))) void*)l, 16, 0, 0);
}

// Merged prep: 7 f32->bf16 conversions (blocks 0..8191) + mask->bits
// (blocks 8192..12287). Both trivially parallel, block-aligned branch.
__global__ __launch_bounds__(256) void prep_all(
    const float* __restrict__ q, const float* __restrict__ k, const float* __restrict__ v,
    const float* __restrict__ wq, const float* __restrict__ wk,
    const float* __restrict__ wv, const float* __restrict__ wo,
    short* __restrict__ dq, short* __restrict__ dk, short* __restrict__ dv,
    short* __restrict__ dwq, short* __restrict__ dwk,
    short* __restrict__ dwv, short* __restrict__ dwo,
    const int* __restrict__ mask, unsigned long long* __restrict__ bits)
{
    int bid = blockIdx.x;
    if (bid < 8192) {
        const float* s; short* d; int base;
        if      (bid < 2048) { s = q;  d = dq;  base = bid; }
        else if (bid < 4096) { s = k;  d = dk;  base = bid - 2048; }
        else if (bid < 6144) { s = v;  d = dv;  base = bid - 4096; }
        else if (bid < 6656) { s = wq; d = dwq; base = bid - 6144; }
        else if (bid < 7168) { s = wk; d = dwk; base = bid - 6656; }
        else if (bid < 7680) { s = wv; d = dwv; base = bid - 7168; }
        else                 { s = wo; d = dwo; base = bid - 7680; }
        int i = base * 256 + threadIdx.x;
        f32x4 a = ((const f32x4*)s)[i * 2];
        f32x4 b = ((const f32x4*)s)[i * 2 + 1];
        short8 o;
        #pragma unroll
        for (int j = 0; j < 4; ++j) { o[j] = f2bf(a[j]); o[4 + j] = f2bf(b[j]); }
        ((short8*)d)[i] = o;
    } else {
        int mid = bid - 8192;            // 0..4095
        const int i = mid & 1023;
        const int b = mid >> 10;
        const int qq = threadIdx.x >> 6;
        const int lane = threadIdx.x & 63;
        const int* mp = &mask[((size_t)b * LN + i) * LN + qq * 256 + lane * 4];
        int4 mv = *(const int4*)mp;
        unsigned long long b0 = __ballot(mv.x != 0);
        unsigned long long b1 = __ballot(mv.y != 0);
        unsigned long long b2 = __ballot(mv.z != 0);
        unsigned long long b3 = __ballot(mv.w != 0);
        if (lane == 0) {
            unsigned long long* o = &bits[(((size_t)b * LN + i) * 4 + qq) * 4];
            o[0] = b0; o[1] = b1; o[2] = b2; o[3] = b3;
        }
    }
}

// ---------- 64^2-tile GEMM body (r12-verified) ----------
// MODE 0: bf16 out; MODE 1: vT transposed out; MODE 2: f32 out.
template<int MODE>
__device__ __forceinline__ void gemm_body(
    const short* __restrict__ A, const short* __restrict__ Bt,
    const float* __restrict__ bias, void* __restrict__ Cp,
    int m0, int n0, int N, int K, short* lA, short* lB)
{
    const int tid = threadIdx.x;
    const int lane = tid & 63;
    const int wid = tid >> 6;
    const int wr = wid >> 1, wc = wid & 1;
    const int lr = lane & 15, lg = lane >> 4;

    int srow[2], skc[2];
    #pragma unroll
    for (int p = 0; p < 2; ++p) {
        int ch = p * 256 + wid * 64 + lane;
        srow[p] = ch >> 3;
        skc[p] = (((ch & 7) ^ (srow[p] & 7))) * 8;
    }

    f32x4 acc[2][2] = {};

    for (int k0 = 0; k0 < K; k0 += 64) {
        #pragma unroll
        for (int p = 0; p < 2; ++p) {
            gl_lds16(A  + (size_t)(m0 + srow[p]) * K + k0 + skc[p], &lA[(p * 256 + wid * 64) * 8]);
            gl_lds16(Bt + (size_t)(n0 + srow[p]) * K + k0 + skc[p], &lB[(p * 256 + wid * 64) * 8]);
        }
        __syncthreads();
        bf16x8 af[2][2], bfr[2][2];
        #pragma unroll
        for (int kh = 0; kh < 2; ++kh) {
            #pragma unroll
            for (int m = 0; m < 2; ++m) {
                int arow = wr * 32 + m * 16 + lr;
                af[kh][m] = *(const bf16x8*)&lA[arow * 64 + (((kh * 4 + lg) ^ (arow & 7)) * 8)];
            }
            #pragma unroll
            for (int n = 0; n < 2; ++n) {
                int brow = wc * 32 + n * 16 + lr;
                bfr[kh][n] = *(const bf16x8*)&lB[brow * 64 + (((kh * 4 + lg) ^ (brow & 7)) * 8)];
            }
        }
        #pragma unroll
        for (int kh = 0; kh < 2; ++kh)
            #pragma unroll
            for (int m = 0; m < 2; ++m)
                #pragma unroll
                for (int n = 0; n < 2; ++n)
                    acc[m][n] = __builtin_amdgcn_mfma_f32_16x16x32_bf16(af[kh][m], bfr[kh][n], acc[m][n], 0, 0, 0);
        __syncthreads();
    }

    #pragma unroll
    for (int m = 0; m < 2; ++m)
        #pragma unroll
        for (int n = 0; n < 2; ++n) {
            int col = n0 + wc * 32 + n * 16 + lr;
            float bb = bias[col];
            if (MODE == 1) {
                int row = m0 + wr * 32 + m * 16 + lg * 4;
                int bb_i = row >> 10, tok = row & 1023;
                int hh = col >> 6, dd = col & 63;
                s16x4 o;
                #pragma unroll
                for (int r = 0; r < 4; ++r) o[r] = f2bf(acc[m][n][r] + bb);
                *(s16x4*)&((short*)Cp)[((size_t)((bb_i * NH + hh) * DKH) + dd) * LN + tok] = o;
            } else {
                #pragma unroll
                for (int r = 0; r < 4; ++r) {
                    int row = m0 + wr * 32 + m * 16 + lg * 4 + r;
                    float v = acc[m][n][r] + bb;
                    if (MODE == 2) ((float*)Cp)[(size_t)row * N + col] = v;
                    else           ((short*)Cp)[(size_t)row * N + col] = f2bf(v);
                }
            }
        }
}

// ---------- 128^2-tile GEMM body (m97 config; fast path, 3 blocks/CU) ----------
template<int MODE>
__device__ __forceinline__ void gemm_body128(
    const short* __restrict__ A, const short* __restrict__ Bt,
    const float* __restrict__ bias, void* __restrict__ Cp,
    int m0, int n0, int N, int K, short* lA, short* lB)   // lA/lB: 128*64 shorts
{
    const int tid = threadIdx.x;
    const int lane = tid & 63;
    const int wid = tid >> 6;
    const int wr = wid >> 1, wc = wid & 1;
    const int lr = lane & 15, lg = lane >> 4;

    int srow[4], skc[4];
    #pragma unroll
    for (int p = 0; p < 4; ++p) {
        int ch = p * 256 + wid * 64 + lane;       // 0..1023
        srow[p] = ch >> 3;                        // 0..127
        skc[p] = (((ch & 7) ^ (srow[p] & 7))) * 8;
    }

    f32x4 acc[4][4] = {};

    for (int k0 = 0; k0 < K; k0 += 64) {
        #pragma unroll
        for (int p = 0; p < 4; ++p) {
            gl_lds16(A  + (size_t)(m0 + srow[p]) * K + k0 + skc[p], &lA[(p * 256 + wid * 64) * 8]);
            gl_lds16(Bt + (size_t)(n0 + srow[p]) * K + k0 + skc[p], &lB[(p * 256 + wid * 64) * 8]);
        }
        __syncthreads();
        #pragma unroll
        for (int kh = 0; kh < 2; ++kh) {
            bf16x8 af[4], bfr[4];
            #pragma unroll
            for (int m = 0; m < 4; ++m) {
                int arow = wr * 64 + m * 16 + lr;
                af[m] = *(const bf16x8*)&lA[arow * 64 + (((kh * 4 + lg) ^ (arow & 7)) * 8)];
            }
            #pragma unroll
            for (int n = 0; n < 4; ++n) {
                int brow = wc * 64 + n * 16 + lr;
                bfr[n] = *(const bf16x8*)&lB[brow * 64 + (((kh * 4 + lg) ^ (brow & 7)) * 8)];
            }
            #pragma unroll
            for (int m = 0; m < 4; ++m)
                #pragma unroll
                for (int n = 0; n < 4; ++n)
                    acc[m][n] = __builtin_amdgcn_mfma_f32_16x16x32_bf16(af[m], bfr[n], acc[m][n], 0, 0, 0);
        }
        __syncthreads();
    }

    #pragma unroll
    for (int m = 0; m < 4; ++m)
        #pragma unroll
        for (int n = 0; n < 4; ++n) {
            int col = n0 + wc * 64 + n * 16 + lr;
            float bb = bias[col];
            if (MODE == 1) {
                int row = m0 + wr * 64 + m * 16 + lg * 4;
                int bb_i = row >> 10, tok = row & 1023;
                int hh = col >> 6, dd = col & 63;
                s16x4 o;
                #pragma unroll
                for (int r = 0; r < 4; ++r) o[r] = f2bf(acc[m][n][r] + bb);
                *(s16x4*)&((short*)Cp)[((size_t)((bb_i * NH + hh) * DKH) + dd) * LN + tok] = o;
            } else {
                #pragma unroll
                for (int r = 0; r < 4; ++r) {
                    int row = m0 + wr * 64 + m * 16 + lg * 4 + r;
                    float v = acc[m][n][r] + bb;
                    if (MODE == 2) ((float*)Cp)[(size_t)row * N + col] = v;
                    else           ((short*)Cp)[(size_t)row * N + col] = f2bf(v);
                }
            }
        }
}

// Fast path: all three projections in one 768-block launch (3 blocks/CU).
__global__ __launch_bounds__(256) void gemm_qkv128(
    const short* __restrict__ vin, const short* __restrict__ qin, const short* __restrict__ kin,
    const short* __restrict__ wv, const short* __restrict__ wq, const short* __restrict__ wk,
    const float* __restrict__ bv, const float* __restrict__ bq, const float* __restrict__ bk,
    short* __restrict__ vT, short* __restrict__ q_bf, short* __restrict__ k_bf)
{
    __shared__ short lA[128 * 64];
    __shared__ short lB[128 * 64];
    const int m0 = blockIdx.y * 128, n0 = blockIdx.x * 128;
    if (blockIdx.z == 0)
        gemm_body128<1>(vin, wv, bv, vT, m0, n0, 1024, 1024, lA, lB);
    else if (blockIdx.z == 1)
        gemm_body128<0>(qin, wq, bq, q_bf, m0, n0, 1024, 1024, lA, lB);
    else
        gemm_body128<0>(kin, wk, bk, k_bf, m0, n0, 1024, 1024, lA, lB);
}

// Fallback: merged V+Q (64^2), K separate.
__global__ __launch_bounds__(256) void gemm_vq(
    const short* __restrict__ vin, const short* __restrict__ qin,
    const short* __restrict__ wv, const short* __restrict__ wq,
    const float* __restrict__ bv, const float* __restrict__ bq,
    short* __restrict__ vT, short* __restrict__ q_bf)
{
    __shared__ short lA[64 * 64];
    __shared__ short lB[64 * 64];
    const int m0 = blockIdx.y * 64, n0 = blockIdx.x * 64;
    if (blockIdx.z == 0)
        gemm_body<1>(vin, wv, bv, vT, m0, n0, 1024, 1024, lA, lB);
    else
        gemm_body<0>(qin, wq, bq, q_bf, m0, n0, 1024, 1024, lA, lB);
}

__global__ __launch_bounds__(256) void gemm_bf(
    const short* __restrict__ A, const short* __restrict__ Bt,
    const float* __restrict__ bias, short* __restrict__ C)
{
    __shared__ short lA[64 * 64];
    __shared__ short lB[64 * 64];
    gemm_body<0>(A, Bt, bias, C, blockIdx.y * 64, blockIdx.x * 64, 1024, 1024, lA, lB);
}

__global__ __launch_bounds__(256) void gemm_out(
    const short* __restrict__ A, const short* __restrict__ Bt,
    const float* __restrict__ bias, float* __restrict__ C)
{
    __shared__ short lA[64 * 64];
    __shared__ short lB[64 * 64];
    gemm_body<2>(A, Bt, bias, C, blockIdx.y * 64, blockIdx.x * 64, 1024, 1024, lA, lB);
}

// attn: one block = 32 i-rows of one (b,h); 512 threads / 8 waves.
// Wave w owns j-octant [w*128, w*128+128) for BOTH row groups (K loads stay
// disjoint across waves — r9's duplication mistake avoided). acc[2][8] = 64
// VGPR/wave -> fits (512,4) bound -> 16 waves/CU (4/SIMD), 2x the r16 TLP.
// PV: wave w -> row-group w>>2, d-quarter w&3 (V 2x-duplicated, L2-hot).
// XCD-swizzled 1D grid (2048). Single barrier.
__global__ __launch_bounds__(512, 4) void attn_kernel(
    const short* __restrict__ qb, const short* __restrict__ kb,
    const short* __restrict__ vT, const unsigned long long* __restrict__ mb,
    float* __restrict__ aw, short* __restrict__ cv)
{
    __shared__ short p_lds[32 * 1024];
    __shared__ float redbuf[8][32];

    const int bid = blockIdx.x;
    const int swz = (bid & 7) * 256 + (bid >> 3);
    const int i0 = (swz & 31) * 32;
    const int h = (swz >> 5) & 15;
    const int b = swz >> 9;

    const int tid = threadIdx.x;
    const int lane = tid & 63;
    const int w = tid >> 6;          // 0..7
    const int lr = lane & 15, lg = lane >> 4;

    // mask bits: wave's j-octant sits in q-quarter w>>1, bit base (w&1)*32.
    // bit l for column j = (w&1)*32 + jf*4 + (lr>>2); c = lr&3.
    unsigned long long Bm[2][4];
    #pragma unroll
    for (int g = 0; g < 2; ++g)
        #pragma unroll
        for (int r = 0; r < 4; ++r)
            Bm[g][r] = mb[(((size_t)b * LN + i0 + g * 16 + lg * 4 + r) * 4 + (w >> 1)) * 4 + (lr & 3)]
                       >> ((w & 1) * 32 + (lr >> 2));

    bf16x8 a0[2], a1[2];
    #pragma unroll
    for (int g = 0; g < 2; ++g) {
        const short* qp = &qb[((size_t)b * LN + i0 + g * 16 + lr) * 1024 + h * 64 + lg * 8];
        a0[g] = *(const bf16x8*)qp;
        a1[g] = *(const bf16x8*)(qp + 32);
    }

    f32x4 acc[2][8];
    #pragma unroll
    for (int g = 0; g < 2; ++g)
        #pragma unroll
        for (int jf = 0; jf < 8; ++jf) acc[g][jf] = f32x4{0.f, 0.f, 0.f, 0.f};

    const size_t krow_base = (size_t)b * LN;
    #pragma unroll
    for (int jf = 0; jf < 8; ++jf) {
        int j0f = w * 128 + jf * 16;
        const short* kp = &kb[(krow_base + j0f + lr) * 1024 + h * 64 + lg * 8];
        bf16x8 b0 = *(const bf16x8*)kp;
        bf16x8 b1 = *(const bf16x8*)(kp + 32);
        acc[0][jf] = __builtin_amdgcn_mfma_f32_16x16x32_bf16(a0[0], b0, acc[0][jf], 0, 0, 0);
        acc[0][jf] = __builtin_amdgcn_mfma_f32_16x16x32_bf16(a1[0], b1, acc[0][jf], 0, 0, 0);
        acc[1][jf] = __builtin_amdgcn_mfma_f32_16x16x32_bf16(a0[1], b0, acc[1][jf], 0, 0, 0);
        acc[1][jf] = __builtin_amdgcn_mfma_f32_16x16x32_bf16(a1[1], b1, acc[1][jf], 0, 0, 0);
    }

    float ps[2][4] = {};
    #pragma unroll
    for (int g = 0; g < 2; ++g)
        #pragma unroll
        for (int jf = 0; jf < 8; ++jf)
            #pragma unroll
            for (int r = 0; r < 4; ++r) {
                float p = ((Bm[g][r] >> (jf * 4)) & 1ULL) ? __expf(acc[g][jf][r] * 0.125f) : 0.0f;
                acc[g][jf][r] = p;
                ps[g][r] += p;
            }

    #pragma unroll
    for (int g = 0; g < 2; ++g)
        #pragma unroll
        for (int r = 0; r < 4; ++r) {
            for (int off = 1; off < 16; off <<= 1) ps[g][r] += __shfl_xor(ps[g][r], off, 64);
        }
    if (lr == 0) {
        #pragma unroll
        for (int g = 0; g < 2; ++g)
            #pragma unroll
            for (int r = 0; r < 4; ++r) redbuf[w][g * 16 + lg * 4 + r] = ps[g][r];
    }

    // unnormalized P -> swizzled bf16 LDS
    #pragma unroll
    for (int g = 0; g < 2; ++g)
        #pragma unroll
        for (int jf = 0; jf < 8; ++jf) {
            int j = w * 128 + jf * 16 + lr;
            #pragma unroll
            for (int r = 0; r < 4; ++r) {
                int row = g * 16 + lg * 4 + r;
                int byte = (row * 2048 + j * 2) ^ ((row & 7) << 4);
                *(short*)((char*)p_lds + byte) = f2bf(acc[g][jf][r]);
            }
        }
    __syncthreads();

    // ---- PV: wave w -> row-group gp = w>>2, d-quarter d0 = (w&3)*16 ----
    const int gp = w >> 2;
    const int d0 = (w & 3) * 16;
    f32x4 accA = {0.f, 0.f, 0.f, 0.f}, accB = {0.f, 0.f, 0.f, 0.f};
    const short* vrow = vT + ((size_t)((b * NH + h) * DKH) + d0 + lr) * LN;
    const int prow = gp * 16 + lr;
    const int pbase = prow * 2048;
    const int pswz = (prow & 7) << 4;
    #pragma unroll
    for (int ks = 0; ks < 32; ks += 2) {
        bf16x8 vb0 = *(const bf16x8*)&vrow[ks * 32 + lg * 8];
        bf16x8 vb1 = *(const bf16x8*)&vrow[(ks + 1) * 32 + lg * 8];
        int byte0 = (pbase + (ks * 32 + lg * 8) * 2) ^ pswz;
        int byte1 = (pbase + ((ks + 1) * 32 + lg * 8) * 2) ^ pswz;
        bf16x8 pa0 = *(const bf16x8*)((char*)p_lds + byte0);
        bf16x8 pa1 = *(const bf16x8*)((char*)p_lds + byte1);
        accA = __builtin_amdgcn_mfma_f32_16x16x32_bf16(pa0, vb0, accA, 0, 0, 0);
        accB = __builtin_amdgcn_mfma_f32_16x16x32_bf16(pa1, vb1, accB, 0, 0, 0);
    }

    float invp[4];
    #pragma unroll
    for (int r = 0; r < 4; ++r) {
        float s = redbuf[0][gp * 16 + lg * 4 + r];
        #pragma unroll
        for (int ww = 1; ww < 8; ++ww) s += redbuf[ww][gp * 16 + lg * 4 + r];
        invp[r] = 1.0f / s;
    }
    #pragma unroll
    for (int r = 0; r < 4; ++r) {
        int irow = i0 + gp * 16 + lg * 4 + r;
        cv[((size_t)b * LN + irow) * 1024 + h * 64 + d0 + lr] = f2bf((accA[r] + accB[r]) * invp[r]);
    }

    // ---- aw: vectorized p_lds readback over 512 threads ----
    {
        const int arow = tid >> 4;        // 0..31
        const int ac0 = tid & 15;
        float s = 0.f;
        #pragma unroll
        for (int ww = 0; ww < 8; ++ww) s += redbuf[ww][arow];
        float ainv = 1.0f / s;
        float* awr = aw + ((size_t)(b * NH + h) * LN + i0 + arow) * LN;
        const int abase = arow * 2048;
        const int aswz = (arow & 7) << 4;
        #pragma unroll
        for (int it = 0; it < 8; ++it) {
            int k = ac0 + it * 16;
            int byte = (abase + k * 16) ^ aswz;
            short8 pv = *(const short8*)((char*)p_lds + byte);
            f32x4 o0, o1;
            #pragma unroll
            for (int j = 0; j < 4; ++j) {
                o0[j] = bf2f(pv[j]) * ainv;
                o1[j] = bf2f(pv[4 + j]) * ainv;
            }
            *(f32x4*)&awr[k * 8] = o0;
            *(f32x4*)&awr[k * 8 + 4] = o1;
        }
    }
}

extern "C" void kernel_launch(void* const* d_in, const int* in_sizes, int n_in,
                              void* d_out, int out_size, void* d_ws, size_t ws_size,
                              hipStream_t stream) {
    (void)in_sizes; (void)n_in; (void)out_size;
    const float* key   = (const float*)d_in[0];
    const float* value = (const float*)d_in[1];
    const float* query = (const float*)d_in[2];
    const int*   mask  = (const int*)d_in[3];
    const float* Wk = (const float*)d_in[4];
    const float* bk = (const float*)d_in[5];
    const float* Wv = (const float*)d_in[6];
    const float* bv = (const float*)d_in[7];
    const float* Wq = (const float*)d_in[8];
    const float* bq = (const float*)d_in[9];
    const float* Wo = (const float*)d_in[10];
    const float* bo = (const float*)d_in[11];

    float* out_cv = (float*)d_out;
    float* out_aw = out_cv + (size_t)4096 * 1024;

    // mask bits (512 KB) at out_cv[0, 0.5 MB); q_bf at out_cv[0.5, 8.5 MB).
    // Nothing writes out_cv until the final gemm_out; attn only reads these.
    unsigned long long* mbits_g = (unsigned long long*)out_cv;
    short* q_bf = (short*)((char*)d_out + (size_t)(1u << 19));

    // Workspace layout (first 40 MB identical in both paths):
    //  [ 0, 8)  qin   | [ 8,16) kin -> cv_bf (attn) | [16,24) vin
    //  [24,32)  wq,wk,wv,wo | [32,40) vT
    // Fast path (ws_size >= 48 MB): k_bf at ws[40,48), merged 3-way 128^2 proj.
    const size_t MB = 1u << 20;
    char* ws = (char*)d_ws;
    short* qin  = (short*)(ws + 0 * MB);
    short* kin  = (short*)(ws + 8 * MB);   short* cv_bf = kin;
    short* vin  = (short*)(ws + 16 * MB);
    short* wq   = (short*)(ws + 24 * MB);
    short* wk   = (short*)(ws + 26 * MB);
    short* wv   = (short*)(ws + 28 * MB);
    short* wo   = (short*)(ws + 30 * MB);
    short* vT   = (short*)(ws + 32 * MB);

    dim3 blk(256);
    prep_all<<<dim3(12288), blk, 0, stream>>>(
        query, key, value, Wq, Wk, Wv, Wo,
        qin, kin, vin, wq, wk, wv, wo,
        mask, mbits_g);

    if (ws_size >= (size_t)48 * MB) {
        short* k_bf = (short*)(ws + 40 * MB);
        gemm_qkv128<<<dim3(8, 32, 3), blk, 0, stream>>>(
            vin, qin, kin, wv, wq, wk, bv, bq, bk, vT, q_bf, k_bf);
        attn_kernel<<<dim3(2048), dim3(512), 0, stream>>>(q_bf, k_bf, vT, mbits_g, out_aw, cv_bf);
    } else {
        short* k_bf = qin;   // qin dead after gemm_vq
        gemm_vq<<<dim3(16, 64, 2), blk, 0, stream>>>(vin, qin, wv, wq, bv, bq, vT, q_bf);
        gemm_bf<<<dim3(16, 64), blk, 0, stream>>>(kin, wk, bk, k_bf);
        attn_kernel<<<dim3(2048), dim3(512), 0, stream>>>(q_bf, k_bf, vT, mbits_g, out_aw, cv_bf);
    }
    gemm_out<<<dim3(16, 64), blk, 0, stream>>>(cv_bf, wo, bo, out_cv);
}

// Round 21
// 208.417 us; speedup vs baseline: 1.0591x; 1.0591x over previous
//
#include <hip/hip_runtime.h>
#include <hip/hip_bf16.h>

typedef __attribute__((ext_vector_type(8))) __bf16 bf16x8;
typedef __attribute__((ext_vector_type(8))) short short8;
typedef __attribute__((ext_vector_type(4))) short s16x4;
typedef __attribute__((ext_vector_type(4))) float f32x4;

#define LN 1024
#define NH 16
#define DKH 64

__device__ __forceinline__ short f2bf(float f) {
    unsigned u = __builtin_bit_cast(unsigned, f);
    u = u + 0x7fffu + ((u >> 16) & 1u);
    return (short)(u >> 16);
}
__device__ __forceinline__ float bf2f(short s) {
    return __builtin_bit_cast(float, ((unsigned)(unsigned short)s) << 16);
}

__device__ __forceinline__ void gl_lds16(const short* g, short* l) {
    __builtin_amdgcn_global_load_lds(
        (const __attribute__((address_space(1))) void*)g,
        (__attribute__((address_space(3))) void*)l, 16, 0, 0);
}

// Merged prep: 7 f32->bf16 conversions (blocks 0..8191) + mask->bits
// (blocks 8192..12287). Both trivially parallel, block-aligned branch.
__global__ __launch_bounds__(256) void prep_all(
    const float* __restrict__ q, const float* __restrict__ k, const float* __restrict__ v,
    const float* __restrict__ wq, const float* __restrict__ wk,
    const float* __restrict__ wv, const float* __restrict__ wo,
    short* __restrict__ dq, short* __restrict__ dk, short* __restrict__ dv,
    short* __restrict__ dwq, short* __restrict__ dwk,
    short* __restrict__ dwv, short* __restrict__ dwo,
    const int* __restrict__ mask, unsigned long long* __restrict__ bits)
{
    int bid = blockIdx.x;
    if (bid < 8192) {
        const float* s; short* d; int base;
        if      (bid < 2048) { s = q;  d = dq;  base = bid; }
        else if (bid < 4096) { s = k;  d = dk;  base = bid - 2048; }
        else if (bid < 6144) { s = v;  d = dv;  base = bid - 4096; }
        else if (bid < 6656) { s = wq; d = dwq; base = bid - 6144; }
        else if (bid < 7168) { s = wk; d = dwk; base = bid - 6656; }
        else if (bid < 7680) { s = wv; d = dwv; base = bid - 7168; }
        else                 { s = wo; d = dwo; base = bid - 7680; }
        int i = base * 256 + threadIdx.x;
        f32x4 a = ((const f32x4*)s)[i * 2];
        f32x4 b = ((const f32x4*)s)[i * 2 + 1];
        short8 o;
        #pragma unroll
        for (int j = 0; j < 4; ++j) { o[j] = f2bf(a[j]); o[4 + j] = f2bf(b[j]); }
        ((short8*)d)[i] = o;
    } else {
        int mid = bid - 8192;            // 0..4095
        const int i = mid & 1023;
        const int b = mid >> 10;
        const int qq = threadIdx.x >> 6;
        const int lane = threadIdx.x & 63;
        const int* mp = &mask[((size_t)b * LN + i) * LN + qq * 256 + lane * 4];
        int4 mv = *(const int4*)mp;
        unsigned long long b0 = __ballot(mv.x != 0);
        unsigned long long b1 = __ballot(mv.y != 0);
        unsigned long long b2 = __ballot(mv.z != 0);
        unsigned long long b3 = __ballot(mv.w != 0);
        if (lane == 0) {
            unsigned long long* o = &bits[(((size_t)b * LN + i) * 4 + qq) * 4];
            o[0] = b0; o[1] = b1; o[2] = b2; o[3] = b3;
        }
    }
}

// ---------- 64^2-tile GEMM body (r12-verified) ----------
// MODE 0: bf16 out; MODE 1: vT transposed out; MODE 2: f32 out.
template<int MODE>
__device__ __forceinline__ void gemm_body(
    const short* __restrict__ A, const short* __restrict__ Bt,
    const float* __restrict__ bias, void* __restrict__ Cp,
    int m0, int n0, int N, int K, short* lA, short* lB)
{
    const int tid = threadIdx.x;
    const int lane = tid & 63;
    const int wid = tid >> 6;
    const int wr = wid >> 1, wc = wid & 1;
    const int lr = lane & 15, lg = lane >> 4;

    int srow[2], skc[2];
    #pragma unroll
    for (int p = 0; p < 2; ++p) {
        int ch = p * 256 + wid * 64 + lane;
        srow[p] = ch >> 3;
        skc[p] = (((ch & 7) ^ (srow[p] & 7))) * 8;
    }

    f32x4 acc[2][2] = {};

    for (int k0 = 0; k0 < K; k0 += 64) {
        #pragma unroll
        for (int p = 0; p < 2; ++p) {
            gl_lds16(A  + (size_t)(m0 + srow[p]) * K + k0 + skc[p], &lA[(p * 256 + wid * 64) * 8]);
            gl_lds16(Bt + (size_t)(n0 + srow[p]) * K + k0 + skc[p], &lB[(p * 256 + wid * 64) * 8]);
        }
        __syncthreads();
        bf16x8 af[2][2], bfr[2][2];
        #pragma unroll
        for (int kh = 0; kh < 2; ++kh) {
            #pragma unroll
            for (int m = 0; m < 2; ++m) {
                int arow = wr * 32 + m * 16 + lr;
                af[kh][m] = *(const bf16x8*)&lA[arow * 64 + (((kh * 4 + lg) ^ (arow & 7)) * 8)];
            }
            #pragma unroll
            for (int n = 0; n < 2; ++n) {
                int brow = wc * 32 + n * 16 + lr;
                bfr[kh][n] = *(const bf16x8*)&lB[brow * 64 + (((kh * 4 + lg) ^ (brow & 7)) * 8)];
            }
        }
        #pragma unroll
        for (int kh = 0; kh < 2; ++kh)
            #pragma unroll
            for (int m = 0; m < 2; ++m)
                #pragma unroll
                for (int n = 0; n < 2; ++n)
                    acc[m][n] = __builtin_amdgcn_mfma_f32_16x16x32_bf16(af[kh][m], bfr[kh][n], acc[m][n], 0, 0, 0);
        __syncthreads();
    }

    #pragma unroll
    for (int m = 0; m < 2; ++m)
        #pragma unroll
        for (int n = 0; n < 2; ++n) {
            int col = n0 + wc * 32 + n * 16 + lr;
            float bb = bias[col];
            if (MODE == 1) {
                int row = m0 + wr * 32 + m * 16 + lg * 4;
                int bb_i = row >> 10, tok = row & 1023;
                int hh = col >> 6, dd = col & 63;
                s16x4 o;
                #pragma unroll
                for (int r = 0; r < 4; ++r) o[r] = f2bf(acc[m][n][r] + bb);
                *(s16x4*)&((short*)Cp)[((size_t)((bb_i * NH + hh) * DKH) + dd) * LN + tok] = o;
            } else {
                #pragma unroll
                for (int r = 0; r < 4; ++r) {
                    int row = m0 + wr * 32 + m * 16 + lg * 4 + r;
                    float v = acc[m][n][r] + bb;
                    if (MODE == 2) ((float*)Cp)[(size_t)row * N + col] = v;
                    else           ((short*)Cp)[(size_t)row * N + col] = f2bf(v);
                }
            }
        }
}

// ---------- 128^2-tile GEMM body (m97 config; fast path, 3 blocks/CU) ----------
template<int MODE>
__device__ __forceinline__ void gemm_body128(
    const short* __restrict__ A, const short* __restrict__ Bt,
    const float* __restrict__ bias, void* __restrict__ Cp,
    int m0, int n0, int N, int K, short* lA, short* lB)   // lA/lB: 128*64 shorts
{
    const int tid = threadIdx.x;
    const int lane = tid & 63;
    const int wid = tid >> 6;
    const int wr = wid >> 1, wc = wid & 1;
    const int lr = lane & 15, lg = lane >> 4;

    int srow[4], skc[4];
    #pragma unroll
    for (int p = 0; p < 4; ++p) {
        int ch = p * 256 + wid * 64 + lane;       // 0..1023
        srow[p] = ch >> 3;                        // 0..127
        skc[p] = (((ch & 7) ^ (srow[p] & 7))) * 8;
    }

    f32x4 acc[4][4] = {};

    for (int k0 = 0; k0 < K; k0 += 64) {
        #pragma unroll
        for (int p = 0; p < 4; ++p) {
            gl_lds16(A  + (size_t)(m0 + srow[p]) * K + k0 + skc[p], &lA[(p * 256 + wid * 64) * 8]);
            gl_lds16(Bt + (size_t)(n0 + srow[p]) * K + k0 + skc[p], &lB[(p * 256 + wid * 64) * 8]);
        }
        __syncthreads();
        #pragma unroll
        for (int kh = 0; kh < 2; ++kh) {
            bf16x8 af[4], bfr[4];
            #pragma unroll
            for (int m = 0; m < 4; ++m) {
                int arow = wr * 64 + m * 16 + lr;
                af[m] = *(const bf16x8*)&lA[arow * 64 + (((kh * 4 + lg) ^ (arow & 7)) * 8)];
            }
            #pragma unroll
            for (int n = 0; n < 4; ++n) {
                int brow = wc * 64 + n * 16 + lr;
                bfr[n] = *(const bf16x8*)&lB[brow * 64 + (((kh * 4 + lg) ^ (brow & 7)) * 8)];
            }
            #pragma unroll
            for (int m = 0; m < 4; ++m)
                #pragma unroll
                for (int n = 0; n < 4; ++n)
                    acc[m][n] = __builtin_amdgcn_mfma_f32_16x16x32_bf16(af[m], bfr[n], acc[m][n], 0, 0, 0);
        }
        __syncthreads();
    }

    #pragma unroll
    for (int m = 0; m < 4; ++m)
        #pragma unroll
        for (int n = 0; n < 4; ++n) {
            int col = n0 + wc * 64 + n * 16 + lr;
            float bb = bias[col];
            if (MODE == 1) {
                int row = m0 + wr * 64 + m * 16 + lg * 4;
                int bb_i = row >> 10, tok = row & 1023;
                int hh = col >> 6, dd = col & 63;
                s16x4 o;
                #pragma unroll
                for (int r = 0; r < 4; ++r) o[r] = f2bf(acc[m][n][r] + bb);
                *(s16x4*)&((short*)Cp)[((size_t)((bb_i * NH + hh) * DKH) + dd) * LN + tok] = o;
            } else {
                #pragma unroll
                for (int r = 0; r < 4; ++r) {
                    int row = m0 + wr * 64 + m * 16 + lg * 4 + r;
                    float v = acc[m][n][r] + bb;
                    if (MODE == 2) ((float*)Cp)[(size_t)row * N + col] = v;
                    else           ((short*)Cp)[(size_t)row * N + col] = f2bf(v);
                }
            }
        }
}

// Fast path: all three projections in one 768-block launch (3 blocks/CU).
__global__ __launch_bounds__(256) void gemm_qkv128(
    const short* __restrict__ vin, const short* __restrict__ qin, const short* __restrict__ kin,
    const short* __restrict__ wv, const short* __restrict__ wq, const short* __restrict__ wk,
    const float* __restrict__ bv, const float* __restrict__ bq, const float* __restrict__ bk,
    short* __restrict__ vT, short* __restrict__ q_bf, short* __restrict__ k_bf)
{
    __shared__ short lA[128 * 64];
    __shared__ short lB[128 * 64];
    const int m0 = blockIdx.y * 128, n0 = blockIdx.x * 128;
    if (blockIdx.z == 0)
        gemm_body128<1>(vin, wv, bv, vT, m0, n0, 1024, 1024, lA, lB);
    else if (blockIdx.z == 1)
        gemm_body128<0>(qin, wq, bq, q_bf, m0, n0, 1024, 1024, lA, lB);
    else
        gemm_body128<0>(kin, wk, bk, k_bf, m0, n0, 1024, 1024, lA, lB);
}

// Fallback: merged V+Q (64^2), K separate.
__global__ __launch_bounds__(256) void gemm_vq(
    const short* __restrict__ vin, const short* __restrict__ qin,
    const short* __restrict__ wv, const short* __restrict__ wq,
    const float* __restrict__ bv, const float* __restrict__ bq,
    short* __restrict__ vT, short* __restrict__ q_bf)
{
    __shared__ short lA[64 * 64];
    __shared__ short lB[64 * 64];
    const int m0 = blockIdx.y * 64, n0 = blockIdx.x * 64;
    if (blockIdx.z == 0)
        gemm_body<1>(vin, wv, bv, vT, m0, n0, 1024, 1024, lA, lB);
    else
        gemm_body<0>(qin, wq, bq, q_bf, m0, n0, 1024, 1024, lA, lB);
}

__global__ __launch_bounds__(256) void gemm_bf(
    const short* __restrict__ A, const short* __restrict__ Bt,
    const float* __restrict__ bias, short* __restrict__ C)
{
    __shared__ short lA[64 * 64];
    __shared__ short lB[64 * 64];
    gemm_body<0>(A, Bt, bias, C, blockIdx.y * 64, blockIdx.x * 64, 1024, 1024, lA, lB);
}

__global__ __launch_bounds__(256) void gemm_out(
    const short* __restrict__ A, const short* __restrict__ Bt,
    const float* __restrict__ bias, float* __restrict__ C)
{
    __shared__ short lA[64 * 64];
    __shared__ short lB[64 * 64];
    gemm_body<2>(A, Bt, bias, C, blockIdx.y * 64, blockIdx.x * 64, 1024, 1024, lA, lB);
}

// attn (r16 4-wave structure, verified local optimum) + isolated s_setprio
// around both MFMA clusters: 2 independent blocks/CU at different phases ->
// scheduler can favor the MFMA-issuing block (m191-positive regime).
__global__ __launch_bounds__(256, 2) void attn_kernel(
    const short* __restrict__ qb, const short* __restrict__ kb,
    const short* __restrict__ vT, const unsigned long long* __restrict__ mb,
    float* __restrict__ aw, short* __restrict__ cv)
{
    __shared__ short p_lds[32 * 1024];
    __shared__ float redbuf[4][32];

    const int bid = blockIdx.x;
    const int swz = (bid & 7) * 256 + (bid >> 3);
    const int i0 = (swz & 31) * 32;
    const int h = (swz >> 5) & 15;
    const int b = swz >> 9;

    const int tid = threadIdx.x;
    const int lane = tid & 63;
    const int w = tid >> 6;
    const int lr = lane & 15, lg = lane >> 4;

    unsigned long long Bm[2][4];
    #pragma unroll
    for (int g = 0; g < 2; ++g)
        #pragma unroll
        for (int r = 0; r < 4; ++r)
            Bm[g][r] = mb[(((size_t)b * LN + i0 + g * 16 + lg * 4 + r) * 4 + w) * 4 + (lr & 3)] >> (lr >> 2);

    bf16x8 a0[2], a1[2];
    #pragma unroll
    for (int g = 0; g < 2; ++g) {
        const short* qp = &qb[((size_t)b * LN + i0 + g * 16 + lr) * 1024 + h * 64 + lg * 8];
        a0[g] = *(const bf16x8*)qp;
        a1[g] = *(const bf16x8*)(qp + 32);
    }

    f32x4 acc[2][16];
    #pragma unroll
    for (int g = 0; g < 2; ++g)
        #pragma unroll
        for (int jf = 0; jf < 16; ++jf) acc[g][jf] = f32x4{0.f, 0.f, 0.f, 0.f};

    const size_t krow_base = (size_t)b * LN;
    __builtin_amdgcn_s_setprio(1);
    #pragma unroll
    for (int jf = 0; jf < 16; ++jf) {
        int j0f = w * 256 + jf * 16;
        const short* kp = &kb[(krow_base + j0f + lr) * 1024 + h * 64 + lg * 8];
        bf16x8 b0 = *(const bf16x8*)kp;
        bf16x8 b1 = *(const bf16x8*)(kp + 32);
        acc[0][jf] = __builtin_amdgcn_mfma_f32_16x16x32_bf16(a0[0], b0, acc[0][jf], 0, 0, 0);
        acc[0][jf] = __builtin_amdgcn_mfma_f32_16x16x32_bf16(a1[0], b1, acc[0][jf], 0, 0, 0);
        acc[1][jf] = __builtin_amdgcn_mfma_f32_16x16x32_bf16(a0[1], b0, acc[1][jf], 0, 0, 0);
        acc[1][jf] = __builtin_amdgcn_mfma_f32_16x16x32_bf16(a1[1], b1, acc[1][jf], 0, 0, 0);
    }
    __builtin_amdgcn_s_setprio(0);

    float ps[2][4] = {};
    #pragma unroll
    for (int g = 0; g < 2; ++g)
        #pragma unroll
        for (int jf = 0; jf < 16; ++jf)
            #pragma unroll
            for (int r = 0; r < 4; ++r) {
                float p = ((Bm[g][r] >> (jf * 4)) & 1ULL) ? __expf(acc[g][jf][r] * 0.125f) : 0.0f;
                acc[g][jf][r] = p;
                ps[g][r] += p;
            }

    #pragma unroll
    for (int g = 0; g < 2; ++g)
        #pragma unroll
        for (int r = 0; r < 4; ++r) {
            for (int off = 1; off < 16; off <<= 1) ps[g][r] += __shfl_xor(ps[g][r], off, 64);
        }
    if (lr == 0) {
        #pragma unroll
        for (int g = 0; g < 2; ++g)
            #pragma unroll
            for (int r = 0; r < 4; ++r) redbuf[w][g * 16 + lg * 4 + r] = ps[g][r];
    }

    #pragma unroll
    for (int g = 0; g < 2; ++g)
        #pragma unroll
        for (int jf = 0; jf < 16; ++jf) {
            int j = w * 256 + jf * 16 + lr;
            #pragma unroll
            for (int r = 0; r < 4; ++r) {
                int row = g * 16 + lg * 4 + r;
                int byte = (row * 2048 + j * 2) ^ ((row & 7) << 4);
                *(short*)((char*)p_lds + byte) = f2bf(acc[g][jf][r]);
            }
        }
    __syncthreads();

    // ---- PV first: MFMA + V-load stream starts at barrier-exit ----
    f32x4 accA[2] = {}, accB[2] = {};
    const int d0 = w * 16;
    const short* vrow = vT + ((size_t)((b * NH + h) * DKH) + d0 + lr) * LN;
    __builtin_amdgcn_s_setprio(1);
    #pragma unroll
    for (int ks = 0; ks < 32; ks += 2) {
        bf16x8 vb0 = *(const bf16x8*)&vrow[ks * 32 + lg * 8];
        bf16x8 vb1 = *(const bf16x8*)&vrow[(ks + 1) * 32 + lg * 8];
        #pragma unroll
        for (int g = 0; g < 2; ++g) {
            int row = g * 16 + lr;
            int byte0 = (row * 2048 + (ks * 32 + lg * 8) * 2) ^ ((row & 7) << 4);
            int byte1 = (row * 2048 + ((ks + 1) * 32 + lg * 8) * 2) ^ ((row & 7) << 4);
            bf16x8 pa0 = *(const bf16x8*)((char*)p_lds + byte0);
            bf16x8 pa1 = *(const bf16x8*)((char*)p_lds + byte1);
            accA[g] = __builtin_amdgcn_mfma_f32_16x16x32_bf16(pa0, vb0, accA[g], 0, 0, 0);
            accB[g] = __builtin_amdgcn_mfma_f32_16x16x32_bf16(pa1, vb1, accB[g], 0, 0, 0);
        }
    }
    __builtin_amdgcn_s_setprio(0);

    float inv[2][4];
    #pragma unroll
    for (int g = 0; g < 2; ++g)
        #pragma unroll
        for (int r = 0; r < 4; ++r) {
            float s = redbuf[0][g * 16 + lg * 4 + r];
            for (int ww = 1; ww < 4; ++ww) s += redbuf[ww][g * 16 + lg * 4 + r];
            inv[g][r] = 1.0f / s;
        }
    #pragma unroll
    for (int g = 0; g < 2; ++g)
        #pragma unroll
        for (int r = 0; r < 4; ++r) {
            int irow = i0 + g * 16 + lg * 4 + r;
            cv[((size_t)b * LN + irow) * 1024 + h * 64 + d0 + lr] = f2bf((accA[g][r] + accB[g][r]) * inv[g][r]);
        }

    // ---- aw: vectorized p_lds readback, drains at kernel end ----
    {
        const int arow = tid >> 3;
        const int ac0 = tid & 7;
        float s = redbuf[0][arow] + redbuf[1][arow] + redbuf[2][arow] + redbuf[3][arow];
        float ainv = 1.0f / s;
        float* awr = aw + ((size_t)(b * NH + h) * LN + i0 + arow) * LN;
        const int abase = arow * 2048;
        const int aswz = (arow & 7) << 4;
        #pragma unroll
        for (int it = 0; it < 16; ++it) {
            int k = ac0 + it * 8;
            int byte = (abase + k * 16) ^ aswz;
            short8 pv = *(const short8*)((char*)p_lds + byte);
            f32x4 o0, o1;
            #pragma unroll
            for (int j = 0; j < 4; ++j) {
                o0[j] = bf2f(pv[j]) * ainv;
                o1[j] = bf2f(pv[4 + j]) * ainv;
            }
            *(f32x4*)&awr[k * 8] = o0;
            *(f32x4*)&awr[k * 8 + 4] = o1;
        }
    }
}

extern "C" void kernel_launch(void* const* d_in, const int* in_sizes, int n_in,
                              void* d_out, int out_size, void* d_ws, size_t ws_size,
                              hipStream_t stream) {
    (void)in_sizes; (void)n_in; (void)out_size;
    const float* key   = (const float*)d_in[0];
    const float* value = (const float*)d_in[1];
    const float* query = (const float*)d_in[2];
    const int*   mask  = (const int*)d_in[3];
    const float* Wk = (const float*)d_in[4];
    const float* bk = (const float*)d_in[5];
    const float* Wv = (const float*)d_in[6];
    const float* bv = (const float*)d_in[7];
    const float* Wq = (const float*)d_in[8];
    const float* bq = (const float*)d_in[9];
    const float* Wo = (const float*)d_in[10];
    const float* bo = (const float*)d_in[11];

    float* out_cv = (float*)d_out;
    float* out_aw = out_cv + (size_t)4096 * 1024;

    // mask bits (512 KB) at out_cv[0, 0.5 MB); q_bf at out_cv[0.5, 8.5 MB).
    // Nothing writes out_cv until the final gemm_out; attn only reads these.
    unsigned long long* mbits_g = (unsigned long long*)out_cv;
    short* q_bf = (short*)((char*)d_out + (size_t)(1u << 19));

    // Workspace layout (first 40 MB identical in both paths):
    //  [ 0, 8)  qin   | [ 8,16) kin -> cv_bf (attn) | [16,24) vin
    //  [24,32)  wq,wk,wv,wo | [32,40) vT
    // Fast path (ws_size >= 48 MB): k_bf at ws[40,48), merged 3-way 128^2 proj.
    const size_t MB = 1u << 20;
    char* ws = (char*)d_ws;
    short* qin  = (short*)(ws + 0 * MB);
    short* kin  = (short*)(ws + 8 * MB);   short* cv_bf = kin;
    short* vin  = (short*)(ws + 16 * MB);
    short* wq   = (short*)(ws + 24 * MB);
    short* wk   = (short*)(ws + 26 * MB);
    short* wv   = (short*)(ws + 28 * MB);
    short* wo   = (short*)(ws + 30 * MB);
    short* vT   = (short*)(ws + 32 * MB);

    dim3 blk(256);
    prep_all<<<dim3(12288), blk, 0, stream>>>(
        query, key, value, Wq, Wk, Wv, Wo,
        qin, kin, vin, wq, wk, wv, wo,
        mask, mbits_g);

    if (ws_size >= (size_t)48 * MB) {
        short* k_bf = (short*)(ws + 40 * MB);
        gemm_qkv128<<<dim3(8, 32, 3), blk, 0, stream>>>(
            vin, qin, kin, wv, wq, wk, bv, bq, bk, vT, q_bf, k_bf);
        attn_kernel<<<dim3(2048), blk, 0, stream>>>(q_bf, k_bf, vT, mbits_g, out_aw, cv_bf);
    } else {
        short* k_bf = qin;   // qin dead after gemm_vq
        gemm_vq<<<dim3(16, 64, 2), blk, 0, stream>>>(vin, qin, wv, wq, bv, bq, vT, q_bf);
        gemm_bf<<<dim3(16, 64), blk, 0, stream>>>(kin, wk, bk, k_bf);
        attn_kernel<<<dim3(2048), blk, 0, stream>>>(q_bf, k_bf, vT, mbits_g, out_aw, cv_bf);
    }
    gemm_out<<<dim3(16, 64), blk, 0, stream>>>(cv_bf, wo, bo, out_cv);
}

// Round 22
// 198.368 us; speedup vs baseline: 1.1127x; 1.0507x over previous
//
#include <hip/hip_runtime.h>
#include <hip/hip_bf16.h>

typedef __attribute__((ext_vector_type(8))) __bf16 bf16x8;
typedef __attribute__((ext_vector_type(8))) short short8;
typedef __attribute__((ext_vector_type(4))) short s16x4;
typedef __attribute__((ext_vector_type(4))) float f32x4;

#define LN 1024
#define NH 16
#define DKH 64

__device__ __forceinline__ short f2bf(float f) {
    unsigned u = __builtin_bit_cast(unsigned, f);
    u = u + 0x7fffu + ((u >> 16) & 1u);
    return (short)(u >> 16);
}
__device__ __forceinline__ float bf2f(short s) {
    return __builtin_bit_cast(float, ((unsigned)(unsigned short)s) << 16);
}

__device__ __forceinline__ void gl_lds16(const short* g, short* l) {
    __builtin_amdgcn_global_load_lds(
        (const __attribute__((address_space(1))) void*)g,
        (__attribute__((address_space(3))) void*)l, 16, 0, 0);
}

// Merged prep: 7 f32->bf16 conversions (blocks 0..8191) + mask->bits
// (blocks 8192..12287). Both trivially parallel, block-aligned branch.
__global__ __launch_bounds__(256) void prep_all(
    const float* __restrict__ q, const float* __restrict__ k, const float* __restrict__ v,
    const float* __restrict__ wq, const float* __restrict__ wk,
    const float* __restrict__ wv, const float* __restrict__ wo,
    short* __restrict__ dq, short* __restrict__ dk, short* __restrict__ dv,
    short* __restrict__ dwq, short* __restrict__ dwk,
    short* __restrict__ dwv, short* __restrict__ dwo,
    const int* __restrict__ mask, unsigned long long* __restrict__ bits)
{
    int bid = blockIdx.x;
    if (bid < 8192) {
        const float* s; short* d; int base;
        if      (bid < 2048) { s = q;  d = dq;  base = bid; }
        else if (bid < 4096) { s = k;  d = dk;  base = bid - 2048; }
        else if (bid < 6144) { s = v;  d = dv;  base = bid - 4096; }
        else if (bid < 6656) { s = wq; d = dwq; base = bid - 6144; }
        else if (bid < 7168) { s = wk; d = dwk; base = bid - 6656; }
        else if (bid < 7680) { s = wv; d = dwv; base = bid - 7168; }
        else                 { s = wo; d = dwo; base = bid - 7680; }
        int i = base * 256 + threadIdx.x;
        f32x4 a = ((const f32x4*)s)[i * 2];
        f32x4 b = ((const f32x4*)s)[i * 2 + 1];
        short8 o;
        #pragma unroll
        for (int j = 0; j < 4; ++j) { o[j] = f2bf(a[j]); o[4 + j] = f2bf(b[j]); }
        ((short8*)d)[i] = o;
    } else {
        int mid = bid - 8192;            // 0..4095
        const int i = mid & 1023;
        const int b = mid >> 10;
        const int qq = threadIdx.x >> 6;
        const int lane = threadIdx.x & 63;
        const int* mp = &mask[((size_t)b * LN + i) * LN + qq * 256 + lane * 4];
        int4 mv = *(const int4*)mp;
        unsigned long long b0 = __ballot(mv.x != 0);
        unsigned long long b1 = __ballot(mv.y != 0);
        unsigned long long b2 = __ballot(mv.z != 0);
        unsigned long long b3 = __ballot(mv.w != 0);
        if (lane == 0) {
            unsigned long long* o = &bits[(((size_t)b * LN + i) * 4 + qq) * 4];
            o[0] = b0; o[1] = b1; o[2] = b2; o[3] = b3;
        }
    }
}

// ---------- 64^2-tile GEMM body (r12-verified) ----------
// MODE 0: bf16 out; MODE 1: vT transposed out; MODE 2: f32 out.
template<int MODE>
__device__ __forceinline__ void gemm_body(
    const short* __restrict__ A, const short* __restrict__ Bt,
    const float* __restrict__ bias, void* __restrict__ Cp,
    int m0, int n0, int N, int K, short* lA, short* lB)
{
    const int tid = threadIdx.x;
    const int lane = tid & 63;
    const int wid = tid >> 6;
    const int wr = wid >> 1, wc = wid & 1;
    const int lr = lane & 15, lg = lane >> 4;

    int srow[2], skc[2];
    #pragma unroll
    for (int p = 0; p < 2; ++p) {
        int ch = p * 256 + wid * 64 + lane;
        srow[p] = ch >> 3;
        skc[p] = (((ch & 7) ^ (srow[p] & 7))) * 8;
    }

    f32x4 acc[2][2] = {};

    for (int k0 = 0; k0 < K; k0 += 64) {
        #pragma unroll
        for (int p = 0; p < 2; ++p) {
            gl_lds16(A  + (size_t)(m0 + srow[p]) * K + k0 + skc[p], &lA[(p * 256 + wid * 64) * 8]);
            gl_lds16(Bt + (size_t)(n0 + srow[p]) * K + k0 + skc[p], &lB[(p * 256 + wid * 64) * 8]);
        }
        __syncthreads();
        bf16x8 af[2][2], bfr[2][2];
        #pragma unroll
        for (int kh = 0; kh < 2; ++kh) {
            #pragma unroll
            for (int m = 0; m < 2; ++m) {
                int arow = wr * 32 + m * 16 + lr;
                af[kh][m] = *(const bf16x8*)&lA[arow * 64 + (((kh * 4 + lg) ^ (arow & 7)) * 8)];
            }
            #pragma unroll
            for (int n = 0; n < 2; ++n) {
                int brow = wc * 32 + n * 16 + lr;
                bfr[kh][n] = *(const bf16x8*)&lB[brow * 64 + (((kh * 4 + lg) ^ (brow & 7)) * 8)];
            }
        }
        #pragma unroll
        for (int kh = 0; kh < 2; ++kh)
            #pragma unroll
            for (int m = 0; m < 2; ++m)
                #pragma unroll
                for (int n = 0; n < 2; ++n)
                    acc[m][n] = __builtin_amdgcn_mfma_f32_16x16x32_bf16(af[kh][m], bfr[kh][n], acc[m][n], 0, 0, 0);
        __syncthreads();
    }

    #pragma unroll
    for (int m = 0; m < 2; ++m)
        #pragma unroll
        for (int n = 0; n < 2; ++n) {
            int col = n0 + wc * 32 + n * 16 + lr;
            float bb = bias[col];
            if (MODE == 1) {
                int row = m0 + wr * 32 + m * 16 + lg * 4;
                int bb_i = row >> 10, tok = row & 1023;
                int hh = col >> 6, dd = col & 63;
                s16x4 o;
                #pragma unroll
                for (int r = 0; r < 4; ++r) o[r] = f2bf(acc[m][n][r] + bb);
                *(s16x4*)&((short*)Cp)[((size_t)((bb_i * NH + hh) * DKH) + dd) * LN + tok] = o;
            } else {
                #pragma unroll
                for (int r = 0; r < 4; ++r) {
                    int row = m0 + wr * 32 + m * 16 + lg * 4 + r;
                    float v = acc[m][n][r] + bb;
                    if (MODE == 2) ((float*)Cp)[(size_t)row * N + col] = v;
                    else           ((short*)Cp)[(size_t)row * N + col] = f2bf(v);
                }
            }
        }
}

// ---------- 128^2-tile GEMM body (m97 config; fast path, 3 blocks/CU) ----------
template<int MODE>
__device__ __forceinline__ void gemm_body128(
    const short* __restrict__ A, const short* __restrict__ Bt,
    const float* __restrict__ bias, void* __restrict__ Cp,
    int m0, int n0, int N, int K, short* lA, short* lB)   // lA/lB: 128*64 shorts
{
    const int tid = threadIdx.x;
    const int lane = tid & 63;
    const int wid = tid >> 6;
    const int wr = wid >> 1, wc = wid & 1;
    const int lr = lane & 15, lg = lane >> 4;

    int srow[4], skc[4];
    #pragma unroll
    for (int p = 0; p < 4; ++p) {
        int ch = p * 256 + wid * 64 + lane;       // 0..1023
        srow[p] = ch >> 3;                        // 0..127
        skc[p] = (((ch & 7) ^ (srow[p] & 7))) * 8;
    }

    f32x4 acc[4][4] = {};

    for (int k0 = 0; k0 < K; k0 += 64) {
        #pragma unroll
        for (int p = 0; p < 4; ++p) {
            gl_lds16(A  + (size_t)(m0 + srow[p]) * K + k0 + skc[p], &lA[(p * 256 + wid * 64) * 8]);
            gl_lds16(Bt + (size_t)(n0 + srow[p]) * K + k0 + skc[p], &lB[(p * 256 + wid * 64) * 8]);
        }
        __syncthreads();
        #pragma unroll
        for (int kh = 0; kh < 2; ++kh) {
            bf16x8 af[4], bfr[4];
            #pragma unroll
            for (int m = 0; m < 4; ++m) {
                int arow = wr * 64 + m * 16 + lr;
                af[m] = *(const bf16x8*)&lA[arow * 64 + (((kh * 4 + lg) ^ (arow & 7)) * 8)];
            }
            #pragma unroll
            for (int n = 0; n < 4; ++n) {
                int brow = wc * 64 + n * 16 + lr;
                bfr[n] = *(const bf16x8*)&lB[brow * 64 + (((kh * 4 + lg) ^ (brow & 7)) * 8)];
            }
            #pragma unroll
            for (int m = 0; m < 4; ++m)
                #pragma unroll
                for (int n = 0; n < 4; ++n)
                    acc[m][n] = __builtin_amdgcn_mfma_f32_16x16x32_bf16(af[m], bfr[n], acc[m][n], 0, 0, 0);
        }
        __syncthreads();
    }

    #pragma unroll
    for (int m = 0; m < 4; ++m)
        #pragma unroll
        for (int n = 0; n < 4; ++n) {
            int col = n0 + wc * 64 + n * 16 + lr;
            float bb = bias[col];
            if (MODE == 1) {
                int row = m0 + wr * 64 + m * 16 + lg * 4;
                int bb_i = row >> 10, tok = row & 1023;
                int hh = col >> 6, dd = col & 63;
                s16x4 o;
                #pragma unroll
                for (int r = 0; r < 4; ++r) o[r] = f2bf(acc[m][n][r] + bb);
                *(s16x4*)&((short*)Cp)[((size_t)((bb_i * NH + hh) * DKH) + dd) * LN + tok] = o;
            } else {
                #pragma unroll
                for (int r = 0; r < 4; ++r) {
                    int row = m0 + wr * 64 + m * 16 + lg * 4 + r;
                    float v = acc[m][n][r] + bb;
                    if (MODE == 2) ((float*)Cp)[(size_t)row * N + col] = v;
                    else           ((short*)Cp)[(size_t)row * N + col] = f2bf(v);
                }
            }
        }
}

// Fast path: all three projections in one 768-block launch (3 blocks/CU).
__global__ __launch_bounds__(256) void gemm_qkv128(
    const short* __restrict__ vin, const short* __restrict__ qin, const short* __restrict__ kin,
    const short* __restrict__ wv, const short* __restrict__ wq, const short* __restrict__ wk,
    const float* __restrict__ bv, const float* __restrict__ bq, const float* __restrict__ bk,
    short* __restrict__ vT, short* __restrict__ q_bf, short* __restrict__ k_bf)
{
    __shared__ short lA[128 * 64];
    __shared__ short lB[128 * 64];
    const int m0 = blockIdx.y * 128, n0 = blockIdx.x * 128;
    if (blockIdx.z == 0)
        gemm_body128<1>(vin, wv, bv, vT, m0, n0, 1024, 1024, lA, lB);
    else if (blockIdx.z == 1)
        gemm_body128<0>(qin, wq, bq, q_bf, m0, n0, 1024, 1024, lA, lB);
    else
        gemm_body128<0>(kin, wk, bk, k_bf, m0, n0, 1024, 1024, lA, lB);
}

// Fallback: merged V+Q (64^2), K separate.
__global__ __launch_bounds__(256) void gemm_vq(
    const short* __restrict__ vin, const short* __restrict__ qin,
    const short* __restrict__ wv, const short* __restrict__ wq,
    const float* __restrict__ bv, const float* __restrict__ bq,
    short* __restrict__ vT, short* __restrict__ q_bf)
{
    __shared__ short lA[64 * 64];
    __shared__ short lB[64 * 64];
    const int m0 = blockIdx.y * 64, n0 = blockIdx.x * 64;
    if (blockIdx.z == 0)
        gemm_body<1>(vin, wv, bv, vT, m0, n0, 1024, 1024, lA, lB);
    else
        gemm_body<0>(qin, wq, bq, q_bf, m0, n0, 1024, 1024, lA, lB);
}

__global__ __launch_bounds__(256) void gemm_bf(
    const short* __restrict__ A, const short* __restrict__ Bt,
    const float* __restrict__ bias, short* __restrict__ C)
{
    __shared__ short lA[64 * 64];
    __shared__ short lB[64 * 64];
    gemm_body<0>(A, Bt, bias, C, blockIdx.y * 64, blockIdx.x * 64, 1024, 1024, lA, lB);
}

__global__ __launch_bounds__(256) void gemm_out(
    const short* __restrict__ A, const short* __restrict__ Bt,
    const float* __restrict__ bias, float* __restrict__ C)
{
    __shared__ short lA[64 * 64];
    __shared__ short lB[64 * 64];
    gemm_body<2>(A, Bt, bias, C, blockIdx.y * 64, blockIdx.x * 64, 1024, 1024, lA, lB);
}

// attn: one block = 32 i-rows of one (b,h); XCD-swizzled 1D grid (2048).
// 4 waves, acc[2][16]; single barrier; PV-before-aw; vectorized aw readback.
__global__ __launch_bounds__(256, 2) void attn_kernel(
    const short* __restrict__ qb, const short* __restrict__ kb,
    const short* __restrict__ vT, const unsigned long long* __restrict__ mb,
    float* __restrict__ aw, short* __restrict__ cv)
{
    __shared__ short p_lds[32 * 1024];
    __shared__ float redbuf[4][32];

    const int bid = blockIdx.x;
    const int swz = (bid & 7) * 256 + (bid >> 3);
    const int i0 = (swz & 31) * 32;
    const int h = (swz >> 5) & 15;
    const int b = swz >> 9;

    const int tid = threadIdx.x;
    const int lane = tid & 63;
    const int w = tid >> 6;
    const int lr = lane & 15, lg = lane >> 4;

    unsigned long long Bm[2][4];
    #pragma unroll
    for (int g = 0; g < 2; ++g)
        #pragma unroll
        for (int r = 0; r < 4; ++r)
            Bm[g][r] = mb[(((size_t)b * LN + i0 + g * 16 + lg * 4 + r) * 4 + w) * 4 + (lr & 3)] >> (lr >> 2);

    bf16x8 a0[2], a1[2];
    #pragma unroll
    for (int g = 0; g < 2; ++g) {
        const short* qp = &qb[((size_t)b * LN + i0 + g * 16 + lr) * 1024 + h * 64 + lg * 8];
        a0[g] = *(const bf16x8*)qp;
        a1[g] = *(const bf16x8*)(qp + 32);
    }

    f32x4 acc[2][16];
    #pragma unroll
    for (int g = 0; g < 2; ++g)
        #pragma unroll
        for (int jf = 0; jf < 16; ++jf) acc[g][jf] = f32x4{0.f, 0.f, 0.f, 0.f};

    const size_t krow_base = (size_t)b * LN;
    #pragma unroll
    for (int jf = 0; jf < 16; ++jf) {
        int j0f = w * 256 + jf * 16;
        const short* kp = &kb[(krow_base + j0f + lr) * 1024 + h * 64 + lg * 8];
        bf16x8 b0 = *(const bf16x8*)kp;
        bf16x8 b1 = *(const bf16x8*)(kp + 32);
        acc[0][jf] = __builtin_amdgcn_mfma_f32_16x16x32_bf16(a0[0], b0, acc[0][jf], 0, 0, 0);
        acc[0][jf] = __builtin_amdgcn_mfma_f32_16x16x32_bf16(a1[0], b1, acc[0][jf], 0, 0, 0);
        acc[1][jf] = __builtin_amdgcn_mfma_f32_16x16x32_bf16(a0[1], b0, acc[1][jf], 0, 0, 0);
        acc[1][jf] = __builtin_amdgcn_mfma_f32_16x16x32_bf16(a1[1], b1, acc[1][jf], 0, 0, 0);
    }

    float ps[2][4] = {};
    #pragma unroll
    for (int g = 0; g < 2; ++g)
        #pragma unroll
        for (int jf = 0; jf < 16; ++jf)
            #pragma unroll
            for (int r = 0; r < 4; ++r) {
                float p = ((Bm[g][r] >> (jf * 4)) & 1ULL) ? __expf(acc[g][jf][r] * 0.125f) : 0.0f;
                acc[g][jf][r] = p;
                ps[g][r] += p;
            }

    #pragma unroll
    for (int g = 0; g < 2; ++g)
        #pragma unroll
        for (int r = 0; r < 4; ++r) {
            for (int off = 1; off < 16; off <<= 1) ps[g][r] += __shfl_xor(ps[g][r], off, 64);
        }
    if (lr == 0) {
        #pragma unroll
        for (int g = 0; g < 2; ++g)
            #pragma unroll
            for (int r = 0; r < 4; ++r) redbuf[w][g * 16 + lg * 4 + r] = ps[g][r];
    }

    #pragma unroll
    for (int g = 0; g < 2; ++g)
        #pragma unroll
        for (int jf = 0; jf < 16; ++jf) {
            int j = w * 256 + jf * 16 + lr;
            #pragma unroll
            for (int r = 0; r < 4; ++r) {
                int row = g * 16 + lg * 4 + r;
                int byte = (row * 2048 + j * 2) ^ ((row & 7) << 4);
                *(short*)((char*)p_lds + byte) = f2bf(acc[g][jf][r]);
            }
        }
    __syncthreads();

    // ---- PV first: MFMA + V-load stream starts at barrier-exit ----
    f32x4 accA[2] = {}, accB[2] = {};
    const int d0 = w * 16;
    const short* vrow = vT + ((size_t)((b * NH + h) * DKH) + d0 + lr) * LN;
    #pragma unroll
    for (int ks = 0; ks < 32; ks += 2) {
        bf16x8 vb0 = *(const bf16x8*)&vrow[ks * 32 + lg * 8];
        bf16x8 vb1 = *(const bf16x8*)&vrow[(ks + 1) * 32 + lg * 8];
        #pragma unroll
        for (int g = 0; g < 2; ++g) {
            int row = g * 16 + lr;
            int byte0 = (row * 2048 + (ks * 32 + lg * 8) * 2) ^ ((row & 7) << 4);
            int byte1 = (row * 2048 + ((ks + 1) * 32 + lg * 8) * 2) ^ ((row & 7) << 4);
            bf16x8 pa0 = *(const bf16x8*)((char*)p_lds + byte0);
            bf16x8 pa1 = *(const bf16x8*)((char*)p_lds + byte1);
            accA[g] = __builtin_amdgcn_mfma_f32_16x16x32_bf16(pa0, vb0, accA[g], 0, 0, 0);
            accB[g] = __builtin_amdgcn_mfma_f32_16x16x32_bf16(pa1, vb1, accB[g], 0, 0, 0);
        }
    }

    float inv[2][4];
    #pragma unroll
    for (int g = 0; g < 2; ++g)
        #pragma unroll
        for (int r = 0; r < 4; ++r) {
            float s = redbuf[0][g * 16 + lg * 4 + r];
            for (int ww = 1; ww < 4; ++ww) s += redbuf[ww][g * 16 + lg * 4 + r];
            inv[g][r] = 1.0f / s;
        }
    #pragma unroll
    for (int g = 0; g < 2; ++g)
        #pragma unroll
        for (int r = 0; r < 4; ++r) {
            int irow = i0 + g * 16 + lg * 4 + r;
            cv[((size_t)b * LN + irow) * 1024 + h * 64 + d0 + lr] = f2bf((accA[g][r] + accB[g][r]) * inv[g][r]);
        }

    // ---- aw: vectorized p_lds readback, drains at kernel end ----
    {
        const int arow = tid >> 3;
        const int ac0 = tid & 7;
        float s = redbuf[0][arow] + redbuf[1][arow] + redbuf[2][arow] + redbuf[3][arow];
        float ainv = 1.0f / s;
        float* awr = aw + ((size_t)(b * NH + h) * LN + i0 + arow) * LN;
        const int abase = arow * 2048;
        const int aswz = (arow & 7) << 4;
        #pragma unroll
        for (int it = 0; it < 16; ++it) {
            int k = ac0 + it * 8;
            int byte = (abase + k * 16) ^ aswz;
            short8 pv = *(const short8*)((char*)p_lds + byte);
            f32x4 o0, o1;
            #pragma unroll
            for (int j = 0; j < 4; ++j) {
                o0[j] = bf2f(pv[j]) * ainv;
                o1[j] = bf2f(pv[4 + j]) * ainv;
            }
            *(f32x4*)&awr[k * 8] = o0;
            *(f32x4*)&awr[k * 8 + 4] = o1;
        }
    }
}

extern "C" void kernel_launch(void* const* d_in, const int* in_sizes, int n_in,
                              void* d_out, int out_size, void* d_ws, size_t ws_size,
                              hipStream_t stream) {
    (void)in_sizes; (void)n_in; (void)out_size;
    const float* key   = (const float*)d_in[0];
    const float* value = (const float*)d_in[1];
    const float* query = (const float*)d_in[2];
    const int*   mask  = (const int*)d_in[3];
    const float* Wk = (const float*)d_in[4];
    const float* bk = (const float*)d_in[5];
    const float* Wv = (const float*)d_in[6];
    const float* bv = (const float*)d_in[7];
    const float* Wq = (const float*)d_in[8];
    const float* bq = (const float*)d_in[9];
    const float* Wo = (const float*)d_in[10];
    const float* bo = (const float*)d_in[11];

    float* out_cv = (float*)d_out;
    float* out_aw = out_cv + (size_t)4096 * 1024;

    // mask bits (512 KB) at out_cv[0, 0.5 MB); q_bf at out_cv[0.5, 8.5 MB).
    // Nothing writes out_cv until the final gemm_out; attn only reads these.
    unsigned long long* mbits_g = (unsigned long long*)out_cv;
    short* q_bf = (short*)((char*)d_out + (size_t)(1u << 19));

    // Workspace layout (first 40 MB identical in both paths):
    //  [ 0, 8)  qin   | [ 8,16) kin -> cv_bf (attn) | [16,24) vin
    //  [24,32)  wq,wk,wv,wo | [32,40) vT
    // Fast path (ws_size >= 48 MB): k_bf at ws[40,48), merged 3-way 128^2 proj.
    const size_t MB = 1u << 20;
    char* ws = (char*)d_ws;
    short* qin  = (short*)(ws + 0 * MB);
    short* kin  = (short*)(ws + 8 * MB);   short* cv_bf = kin;
    short* vin  = (short*)(ws + 16 * MB);
    short* wq   = (short*)(ws + 24 * MB);
    short* wk   = (short*)(ws + 26 * MB);
    short* wv   = (short*)(ws + 28 * MB);
    short* wo   = (short*)(ws + 30 * MB);
    short* vT   = (short*)(ws + 32 * MB);

    dim3 blk(256);
    prep_all<<<dim3(12288), blk, 0, stream>>>(
        query, key, value, Wq, Wk, Wv, Wo,
        qin, kin, vin, wq, wk, wv, wo,
        mask, mbits_g);

    if (ws_size >= (size_t)48 * MB) {
        short* k_bf = (short*)(ws + 40 * MB);
        gemm_qkv128<<<dim3(8, 32, 3), blk, 0, stream>>>(
            vin, qin, kin, wv, wq, wk, bv, bq, bk, vT, q_bf, k_bf);
        attn_kernel<<<dim3(2048), blk, 0, stream>>>(q_bf, k_bf, vT, mbits_g, out_aw, cv_bf);
    } else {
        short* k_bf = qin;   // qin dead after gemm_vq
        gemm_vq<<<dim3(16, 64, 2), blk, 0, stream>>>(vin, qin, wv, wq, bv, bq, vT, q_bf);
        gemm_bf<<<dim3(16, 64), blk, 0, stream>>>(kin, wk, bk, k_bf);
        attn_kernel<<<dim3(2048), blk, 0, stream>>>(q_bf, k_bf, vT, mbits_g, out_aw, cv_bf);
    }
    gemm_out<<<dim3(16, 64), blk, 0, stream>>>(cv_bf, wo, bo, out_cv);
}